// Round 6
// baseline (245.224 us; speedup 1.0000x reference)
//
#include <hip/hip_runtime.h>
#include <hip/hip_bf16.h>
#include <stdint.h>

#define M_ROWS 8192
#define K_DIM  1024
#define N_COLS 4096
#define N_CLUS 64

typedef short bf16x8 __attribute__((ext_vector_type(8)));
typedef float f32x4  __attribute__((ext_vector_type(4)));

__device__ __forceinline__ unsigned short f2bf(float f) {
  unsigned int u = __float_as_uint(f);
  unsigned int r = (u + 0x7FFFu + ((u >> 16) & 1u)) >> 16;
  return (unsigned short)r;
}

// ---------------- fp32 -> bf16 conversion (x, W, centroids) + mask init ----------------
__global__ __launch_bounds__(256) void convert_kernel(
    const float* __restrict__ x, const float* __restrict__ wgt,
    const float* __restrict__ cent,
    unsigned short* __restrict__ xb, unsigned short* __restrict__ wb,
    unsigned short* __restrict__ cb,
    unsigned long long* __restrict__ mask) {
  const size_t g = (size_t)blockIdx.x * 256 + threadIdx.x;
  if (g == 0) *mask = 0ull;   // stream-ordered before routing's atomicOr
  const size_t NXG = (size_t)M_ROWS * K_DIM / 4;
  const size_t NWG = (size_t)N_COLS * K_DIM / 4;
  const float* src; unsigned short* dst; size_t gg;
  if (g < NXG)            { src = x;    dst = xb; gg = g; }
  else if (g < NXG + NWG) { src = wgt;  dst = wb; gg = g - NXG; }
  else                    { src = cent; dst = cb; gg = g - NXG - NWG; }
  const float4 v = *(const float4*)&src[gg * 4];
  ushort4 o;
  o.x = f2bf(v.x); o.y = f2bf(v.y); o.z = f2bf(v.z); o.w = f2bf(v.w);
  *(ushort4*)&dst[gg * 4] = o;
}

// ---------------- routing via MFMA: cluster-active 64-bit mask ----------------
// 256 blocks x 1 wave x 32 rows. logits = x @ C^T, bf16 MFMA.
__global__ __launch_bounds__(64) void routing_mfma_kernel(
    const unsigned short* __restrict__ xb, const unsigned short* __restrict__ cb,
    unsigned long long* __restrict__ mask) {
  __shared__ unsigned short Xl[32 * 32];   // 2 KB
  __shared__ unsigned short Cl[64 * 32];   // 4 KB
  const int t = threadIdx.x;
  const int lr = t & 15;
  const int lk = (t >> 4) * 8;
  const int row0 = blockIdx.x * 32;

  f32x4 acc[2][4];
  #pragma unroll
  for (int i = 0; i < 2; ++i)
    #pragma unroll
    for (int j = 0; j < 4; ++j) acc[i][j] = {0.f, 0.f, 0.f, 0.f};

  for (int kt = 0; kt < K_DIM / 32; ++kt) {
    #pragma unroll
    for (int it = 0; it < 2; ++it) {       // X: 32 rows x 32 k
      const int tt = it * 64 + t;
      const int row = tt >> 2;
      const int kc = (tt & 3) * 8;
      const unsigned short* gx = xb + (size_t)(row0 + row) * K_DIM + kt * 32 + kc;
      char* lx = (char*)Xl + it * 1024;
      __builtin_amdgcn_global_load_lds((const __attribute__((address_space(1))) void*)gx,
                                       (__attribute__((address_space(3))) void*)lx, 16, 0, 0);
    }
    #pragma unroll
    for (int it = 0; it < 4; ++it) {       // C: 64 rows x 32 k
      const int tt = it * 64 + t;
      const int row = tt >> 2;
      const int kc = (tt & 3) * 8;
      const unsigned short* gc = cb + (size_t)row * K_DIM + kt * 32 + kc;
      char* lc = (char*)Cl + it * 1024;
      __builtin_amdgcn_global_load_lds((const __attribute__((address_space(1))) void*)gc,
                                       (__attribute__((address_space(3))) void*)lc, 16, 0, 0);
    }
    __syncthreads();

    bf16x8 af[2], cf[4];
    #pragma unroll
    for (int mi = 0; mi < 2; ++mi)
      af[mi] = *(const bf16x8*)&Xl[(mi * 16 + lr) * 32 + lk];
    #pragma unroll
    for (int ni = 0; ni < 4; ++ni)
      cf[ni] = *(const bf16x8*)&Cl[(ni * 16 + lr) * 32 + lk];
    #pragma unroll
    for (int mi = 0; mi < 2; ++mi)
      #pragma unroll
      for (int ni = 0; ni < 4; ++ni)
        acc[mi][ni] = __builtin_amdgcn_mfma_f32_16x16x32_bf16(af[mi], cf[ni], acc[mi][ni], 0, 0, 0);
    __syncthreads();
  }

  bool colflag[4] = {false, false, false, false};
  #pragma unroll
  for (int mi = 0; mi < 2; ++mi) {
    #pragma unroll
    for (int j = 0; j < 4; ++j) {
      const float v0 = acc[mi][0][j], v1 = acc[mi][1][j],
                  v2 = acc[mi][2][j], v3 = acc[mi][3][j];
      float m = fmaxf(fmaxf(v0, v1), fmaxf(v2, v3));
      #pragma unroll
      for (int off = 8; off >= 1; off >>= 1) m = fmaxf(m, __shfl_xor(m, off));
      float S = expf(v0 - m) + expf(v1 - m) + expf(v2 - m) + expf(v3 - m);
      #pragma unroll
      for (int off = 8; off >= 1; off >>= 1) S += __shfl_xor(S, off);
      const float thr = logf(1e-4f * S);
      colflag[0] |= (v0 - m) > thr;
      colflag[1] |= (v1 - m) > thr;
      colflag[2] |= (v2 - m) > thr;
      colflag[3] |= (v3 - m) > thr;
    }
  }
  unsigned long long bits = 0;
  #pragma unroll
  for (int ni = 0; ni < 4; ++ni) {
    unsigned long long u = __ballot(colflag[ni]);
    u |= u >> 32; u |= u >> 16;
    bits |= (u & 0xFFFFull) << (ni * 16);
  }
  if (t == 0) atomicOr(mask, bits);
}

// ---------------- 256x256 8-phase bf16 MFMA GEMM, reg-prefetch pipeline ----------------
// Fragments for phase p+1 are ds_read during phase p into alternate static
// slots (afE/afO, bB0/bB1); MFMAs consume regs loaded last phase -> no
// in-phase lgkm dependency. Waits (outstanding-queue trace): end-P3:6 P4:4
// P7:6 P8:4; never 0 in the loop.
__global__ __launch_bounds__(512, 1) void gemm_kernel(
    const unsigned short* __restrict__ xb, const unsigned short* __restrict__ wb,
    const float* __restrict__ bias, const int* __restrict__ assign,
    const unsigned long long* __restrict__ maskp,
    float* __restrict__ out) {
  __shared__ unsigned short lds[2][2][2][128 * 64];   // 128 KB

  const int t = threadIdx.x;
  const int l = t & 63;
  const int w = t >> 6;          // 0..7
  const int wm = w & 1;
  const int wn = w >> 1;         // 0..3
  const int lr = l & 15;
  const int hi4 = l >> 4;        // 0..3

  const int bid = blockIdx.x;
  const int swz = (bid & 7) * (gridDim.x >> 3) + (bid >> 3);   // 512 % 8 == 0
  const int bm = swz >> 4, bn = swz & 15;                      // 32 x 16 tiles
  const int m0 = bm * 256, n0 = bn * 256;

  f32x4 acc[8][4];
  #pragma unroll
  for (int i = 0; i < 8; ++i)
    #pragma unroll
    for (int j = 0; j < 4; ++j) acc[i][j] = {0.f, 0.f, 0.f, 0.f};

  bf16x8 afE[4][2], afO[4][2];   // A-half0 / A-half1 slots
  bf16x8 bB0[2][2], bB1[2][2];   // B-half0 / B-half1 slots

#define STAGE(OP, D, H, KT) do {                                               \
    const unsigned short* _src = (OP) ? wb : xb;                               \
    const int _rb = ((OP) ? n0 : m0) + (H) * 128;                              \
    _Pragma("unroll")                                                          \
    for (int _j = 0; _j < 2; ++_j) {                                           \
      const int _p = _j * 512 + t;                                             \
      const int _row = _p >> 3;                                                \
      const int _ch = (_p & 7) ^ (_row & 7);                                   \
      const unsigned short* _g = _src + (size_t)(_rb + _row) * K_DIM           \
                                 + (KT) * 64 + _ch * 8;                        \
      char* _d = (char*)&lds[D][OP][H][0] + _j * 8192 + w * 1024;              \
      __builtin_amdgcn_global_load_lds(                                        \
          (const __attribute__((address_space(1))) void*)_g,                   \
          (__attribute__((address_space(3))) void*)_d, 16, 0, 0);              \
    }                                                                          \
  } while (0)

#define LDA(D, H, DST) do {                                                    \
    _Pragma("unroll")                                                          \
    for (int _mi = 0; _mi < 4; ++_mi) {                                        \
      const int _row = _mi * 32 + wm * 16 + lr;                                \
      _Pragma("unroll")                                                        \
      for (int _kk = 0; _kk < 2; ++_kk) {                                      \
        const int _ch = (_kk * 4 + hi4) ^ (_row & 7);                          \
        DST[_mi][_kk] = *(const bf16x8*)&lds[D][0][H][_row * 64 + _ch * 8];    \
      }                                                                        \
    }                                                                          \
  } while (0)

#define LDB(D, H, DST) do {                                                    \
    _Pragma("unroll")                                                          \
    for (int _ni = 0; _ni < 2; ++_ni) {                                        \
      const int _row = _ni * 64 + wn * 16 + lr;                                \
      _Pragma("unroll")                                                        \
      for (int _kk = 0; _kk < 2; ++_kk) {                                      \
        const int _ch = (_kk * 4 + hi4) ^ (_row & 7);                          \
        DST[_ni][_kk] = *(const bf16x8*)&lds[D][1][H][_row * 64 + _ch * 8];    \
      }                                                                        \
    }                                                                          \
  } while (0)

#define MFMAQ(QM, QN, AF, BF) do {                                             \
    __builtin_amdgcn_s_setprio(1);                                             \
    _Pragma("unroll")                                                          \
    for (int _kk = 0; _kk < 2; ++_kk)                                          \
      _Pragma("unroll")                                                        \
      for (int _mi = 0; _mi < 4; ++_mi)                                        \
        _Pragma("unroll")                                                      \
        for (int _ni = 0; _ni < 2; ++_ni)                                      \
          acc[(QM)*4 + _mi][(QN)*2 + _ni] =                                    \
              __builtin_amdgcn_mfma_f32_16x16x32_bf16(                         \
                  AF[_mi][_kk], BF[_ni][_kk],                                  \
                  acc[(QM)*4 + _mi][(QN)*2 + _ni], 0, 0, 0);                   \
    __builtin_amdgcn_s_setprio(0);                                             \
  } while (0)

#define WAITV(N) asm volatile("s_waitcnt vmcnt(" #N ")" ::: "memory")
#define BAR() do { asm volatile("" ::: "memory"); __builtin_amdgcn_s_barrier(); } while (0)

  // ---- prologue: stage tile0 fully + tile1 half0; preload P1's fragments ----
  STAGE(0, 0, 0, 0);   // A0(0)
  STAGE(1, 0, 0, 0);   // B0(0)
  STAGE(0, 0, 1, 0);   // A1(0)
  STAGE(1, 0, 1, 0);   // B1(0)
  STAGE(0, 1, 0, 1);   // A0(1)
  STAGE(1, 1, 0, 1);   // B0(1)
  WAITV(4);            // tile0 all landed; A0(1),B0(1) in flight
  BAR();
  LDA(0, 0, afE);      // A0(0)
  LDB(0, 0, bB0);      // B0(0)

  // ---- main loop: iterations 0..6 (tiles e=2i -> dbuf0, o=2i+1 -> dbuf1) ----
  for (int i = 0; i < 7; ++i) {
    const int k1 = 2 * i + 1, k2 = 2 * i + 2, k3 = 2 * i + 3;
    // P1: prefetch B1(e); MFMA (A0e,B0e)
    LDB(0, 1, bB1); STAGE(0, 1, 1, k1); MFMAQ(0, 0, afE, bB0); BAR();
    // P2: prefetch A1(e); MFMA (A0e,B1e)
    LDA(0, 1, afO); STAGE(1, 1, 1, k1); MFMAQ(0, 1, afE, bB1); BAR();
    // P3: MFMA (A1e,B0e); end-wait covers P4's reads of A0(o),B0(o)
    STAGE(0, 0, 0, k2); MFMAQ(1, 0, afO, bB0); WAITV(6); BAR();
    // P4: prefetch A0(o),B0(o); MFMA (A1e,B1e); end-wait covers P5's B1(o)
    LDA(1, 0, afE); LDB(1, 0, bB0); STAGE(1, 0, 0, k2);
    MFMAQ(1, 1, afO, bB1); WAITV(4); BAR();
    // P5: prefetch B1(o); MFMA (A0o,B0o)
    LDB(1, 1, bB1); STAGE(0, 0, 1, k2); MFMAQ(0, 0, afE, bB0); BAR();
    // P6: prefetch A1(o); MFMA (A0o,B1o)
    LDA(1, 1, afO); STAGE(1, 0, 1, k2); MFMAQ(0, 1, afE, bB1); BAR();
    // P7: MFMA (A1o,B0o); end-wait covers P8's reads of A0(e'),B0(e')
    STAGE(0, 1, 0, k3); MFMAQ(1, 0, afO, bB0); WAITV(6); BAR();
    // P8: prefetch A0(e'),B0(e'); MFMA (A1o,B1o); end-wait covers next-P1's B1(e')
    LDA(0, 0, afE); LDB(0, 0, bB0); STAGE(1, 1, 0, k3);
    MFMAQ(1, 1, afO, bB1); WAITV(4); BAR();
  }

  // ---- tail: tiles 14 (dbuf0), 15 (dbuf1) ----
  // T1
  LDB(0, 1, bB1); STAGE(0, 1, 1, 15); MFMAQ(0, 0, afE, bB0); BAR();
  // T2
  LDA(0, 1, afO); STAGE(1, 1, 1, 15); MFMAQ(0, 1, afE, bB1); BAR();
  // T3: end-wait covers T4's reads of A0(15),B0(15)
  MFMAQ(1, 0, afO, bB0); WAITV(4); BAR();
  // T4: end-wait covers T5's B1(15) (and T6's A1(15))
  LDA(1, 0, afE); LDB(1, 0, bB0); MFMAQ(1, 1, afO, bB1); WAITV(0); BAR();
  // T5
  LDB(1, 1, bB1); MFMAQ(0, 0, afE, bB0); BAR();
  // T6
  LDA(1, 1, afO); MFMAQ(0, 1, afE, bB1); BAR();
  // T7
  MFMAQ(1, 0, afO, bB0); BAR();
  // T8
  MFMAQ(1, 1, afO, bB1);

  // ---- epilogue: fused mask + bias ----
  const unsigned long long mask = *maskp;
  #pragma unroll
  for (int ni = 0; ni < 4; ++ni) {
    const int col = n0 + ni * 64 + wn * 16 + lr;
    const int a = assign[col];
    const bool act = (mask >> a) & 1ull;
    const float bv = bias[col];
    #pragma unroll
    for (int mi = 0; mi < 8; ++mi) {
      const int rowb = m0 + mi * 32 + wm * 16 + hi4 * 4;
      #pragma unroll
      for (int j = 0; j < 4; ++j) {
        out[(size_t)(rowb + j) * N_COLS + col] = act ? (acc[mi][ni][j] + bv) : 0.0f;
      }
    }
  }
#undef STAGE
#undef LDA
#undef LDB
#undef MFMAQ
#undef WAITV
#undef BAR
}

extern "C" void kernel_launch(void* const* d_in, const int* in_sizes, int n_in,
                              void* d_out, int out_size, void* d_ws, size_t ws_size,
                              hipStream_t stream) {
  const float* x    = (const float*)d_in[0];
  const float* wgt  = (const float*)d_in[1];
  const float* bias = (const float*)d_in[2];
  const float* cent = (const float*)d_in[3];
  const int* assign = (const int*)d_in[4];
  float* out = (float*)d_out;

  unsigned long long* mask = (unsigned long long*)d_ws;
  unsigned short* xb = (unsigned short*)((char*)d_ws + 256);
  unsigned short* wb = xb + (size_t)M_ROWS * K_DIM;
  unsigned short* cb = wb + (size_t)N_COLS * K_DIM;

  const int ngroups = (M_ROWS * K_DIM + N_COLS * K_DIM + N_CLUS * K_DIM) / 4;
  hipLaunchKernelGGL(convert_kernel, dim3(ngroups / 256), dim3(256), 0, stream,
                     x, wgt, cent, xb, wb, cb, mask);
  hipLaunchKernelGGL(routing_mfma_kernel, dim3(M_ROWS / 32), dim3(64), 0, stream,
                     xb, cb, mask);
  hipLaunchKernelGGL(gemm_kernel, dim3((M_ROWS / 256) * (N_COLS / 256)), dim3(512), 0, stream,
                     xb, wb, bias, assign, mask, out);
}

// Round 7
// 107.262 us; speedup vs baseline: 2.2862x; 2.2862x over previous
//
#include <hip/hip_runtime.h>
#include <hip/hip_bf16.h>
#include <stdint.h>

#define M_ROWS 8192
#define K_DIM  1024
#define N_COLS 4096
#define N_CLUS 64

// fragment-native layout (16B groups of 8 bf16):
// A: [bm(32)][kt(16)][kk(2)][Ha(2)][mi(4)][wm(2)][l(64)]  -> 32768 groups / bm
// B: [bn(16)][kt(16)][kk(2)][Hb(2)][ni(2)][wn(4)][l(64)]  -> 32768 groups / bn
// group (.,l) holds src[row][k0..k0+8), row/k0 per decode below.
#define A_GROUPS (32u * 32768u)   // 1048576
#define B_GROUPS (16u * 32768u)   // 524288
#define C_GROUPS (64u * 128u)     // 8192

typedef short bf16x8 __attribute__((ext_vector_type(8)));
typedef float f32x4  __attribute__((ext_vector_type(4)));

__device__ __forceinline__ unsigned short f2bf(float f) {
  unsigned int u = __float_as_uint(f);
  unsigned int r = (u + 0x7FFFu + ((u >> 16) & 1u)) >> 16;
  return (unsigned short)r;
}

// ---------------- fp32 -> bf16 native-layout conversion + mask init ----------------
__global__ __launch_bounds__(256) void convert_kernel(
    const float* __restrict__ x, const float* __restrict__ wgt,
    const float* __restrict__ cent,
    unsigned short* __restrict__ an, unsigned short* __restrict__ bnat,
    unsigned short* __restrict__ cb,
    unsigned long long* __restrict__ mask) {
  const unsigned g = blockIdx.x * 256 + threadIdx.x;
  if (g == 0) *mask = 0ull;
  const float* src; unsigned short* dst; unsigned row, k0;
  if (g < A_GROUPS) {
    const unsigned o = g;
    const unsigned l = o & 63, wm = (o >> 6) & 1, mi = (o >> 7) & 3,
                   Ha = (o >> 9) & 1, kk = (o >> 10) & 1, kt = (o >> 11) & 15,
                   bm = o >> 15;
    row = bm * 256 + Ha * 128 + mi * 32 + wm * 16 + (l & 15);
    k0  = kt * 64 + (kk * 4 + (l >> 4)) * 8;
    src = x; dst = an + (size_t)o * 8;
  } else if (g < A_GROUPS + B_GROUPS) {
    const unsigned o = g - A_GROUPS;
    const unsigned l = o & 63, wn = (o >> 6) & 3, ni = (o >> 8) & 1,
                   Hb = (o >> 9) & 1, kk = (o >> 10) & 1, kt = (o >> 11) & 15,
                   bn = o >> 15;
    row = bn * 256 + Hb * 128 + ni * 64 + wn * 16 + (l & 15);
    k0  = kt * 64 + (kk * 4 + (l >> 4)) * 8;
    src = wgt; dst = bnat + (size_t)o * 8;
  } else {
    const unsigned o = g - A_GROUPS - B_GROUPS;
    row = o >> 7; k0 = (o & 127) * 8;
    src = cent; dst = cb + (size_t)o * 8;
  }
  const float4 v0 = *(const float4*)&src[(size_t)row * K_DIM + k0];
  const float4 v1 = *(const float4*)&src[(size_t)row * K_DIM + k0 + 4];
  union { unsigned short u[8]; uint4 q; } o16;
  o16.u[0] = f2bf(v0.x); o16.u[1] = f2bf(v0.y); o16.u[2] = f2bf(v0.z); o16.u[3] = f2bf(v0.w);
  o16.u[4] = f2bf(v1.x); o16.u[5] = f2bf(v1.y); o16.u[6] = f2bf(v1.z); o16.u[7] = f2bf(v1.w);
  *(uint4*)dst = o16.q;
}

// ---------------- routing (reads native A layout): cluster-active mask ----------------
// 256 blocks x 1 wave; block = (bm, Ha, mi) -> 32 rows. logits = x @ C^T.
__global__ __launch_bounds__(64) void routing_mfma_kernel(
    const unsigned short* __restrict__ an, const unsigned short* __restrict__ cb,
    unsigned long long* __restrict__ mask) {
  __shared__ unsigned short Xl[2048];   // 4 KB: groups [kk][wm][l]
  __shared__ unsigned short Cl[4096];   // 8 KB: groups [(kk*64+row)*4+hi4]
  const int t = threadIdx.x;
  const int lr = t & 15;
  const int hi4 = t >> 4;
  const int bm = blockIdx.x >> 3, Ha = (blockIdx.x >> 2) & 1, mi = blockIdx.x & 3;
  const size_t abase = ((size_t)bm * 32768 + Ha * 512 + mi * 128) * 8;

  f32x4 acc[2][4];
  #pragma unroll
  for (int i = 0; i < 2; ++i)
    #pragma unroll
    for (int j = 0; j < 4; ++j) acc[i][j] = {0.f, 0.f, 0.f, 0.f};

  for (int kt = 0; kt < 16; ++kt) {
    #pragma unroll
    for (int kk2 = 0; kk2 < 2; ++kk2)
      #pragma unroll
      for (int wm2 = 0; wm2 < 2; ++wm2) {
        const unsigned short* gx = an + abase + (size_t)(kt * 2048 + kk2 * 1024 + wm2 * 64) * 8;
        char* dx = (char*)Xl + (kk2 * 128 + wm2 * 64) * 16;
        __builtin_amdgcn_global_load_lds((const __attribute__((address_space(1))) void*)gx,
                                         (__attribute__((address_space(3))) void*)dx, 16, 0, 0);
      }
    #pragma unroll
    for (int r = 0; r < 8; ++r) {
      const int flat = r * 64 + t;
      const int ckk = flat >> 8, crow = (flat >> 2) & 63, chi = flat & 3;
      const unsigned short* gc = cb + (size_t)crow * K_DIM + kt * 64 + ckk * 32 + chi * 8;
      char* dc = (char*)Cl + r * 1024;
      __builtin_amdgcn_global_load_lds((const __attribute__((address_space(1))) void*)gc,
                                       (__attribute__((address_space(3))) void*)dc, 16, 0, 0);
    }
    __syncthreads();

    #pragma unroll
    for (int kk = 0; kk < 2; ++kk) {
      bf16x8 af[2], cf[4];
      #pragma unroll
      for (int wm2 = 0; wm2 < 2; ++wm2)
        af[wm2] = *(const bf16x8*)&Xl[kk * 1024 + wm2 * 512 + t * 8];
      #pragma unroll
      for (int ni = 0; ni < 4; ++ni)
        cf[ni] = *(const bf16x8*)&Cl[kk * 2048 + (ni * 16 + lr) * 32 + hi4 * 8];
      #pragma unroll
      for (int wm2 = 0; wm2 < 2; ++wm2)
        #pragma unroll
        for (int ni = 0; ni < 4; ++ni)
          acc[wm2][ni] = __builtin_amdgcn_mfma_f32_16x16x32_bf16(af[wm2], cf[ni], acc[wm2][ni], 0, 0, 0);
    }
    __syncthreads();
  }

  bool colflag[4] = {false, false, false, false};
  #pragma unroll
  for (int wm2 = 0; wm2 < 2; ++wm2) {
    #pragma unroll
    for (int j = 0; j < 4; ++j) {
      const float v0 = acc[wm2][0][j], v1 = acc[wm2][1][j],
                  v2 = acc[wm2][2][j], v3 = acc[wm2][3][j];
      float m = fmaxf(fmaxf(v0, v1), fmaxf(v2, v3));
      #pragma unroll
      for (int off = 8; off >= 1; off >>= 1) m = fmaxf(m, __shfl_xor(m, off));
      float S = expf(v0 - m) + expf(v1 - m) + expf(v2 - m) + expf(v3 - m);
      #pragma unroll
      for (int off = 8; off >= 1; off >>= 1) S += __shfl_xor(S, off);
      const float thr = logf(1e-4f * S);
      colflag[0] |= (v0 - m) > thr;
      colflag[1] |= (v1 - m) > thr;
      colflag[2] |= (v2 - m) > thr;
      colflag[3] |= (v3 - m) > thr;
    }
  }
  unsigned long long bits = 0;
  #pragma unroll
  for (int ni = 0; ni < 4; ++ni) {
    unsigned long long u = __ballot(colflag[ni]);
    u |= u >> 32; u |= u >> 16;
    bits |= (u & 0xFFFFull) << (ni * 16);
  }
  if (t == 0) atomicOr(mask, bits);
}

// ---------------- LDS-free bf16 MFMA GEMM: direct fragment loads from L2 ----------------
// No __shared__, no barriers. 2-slot pipeline over 32 k32-steps; the compiler's
// precise vmcnt counting provides the T4 semantics (no barrier to defeat it).
__global__ __launch_bounds__(512, 2) void gemm_kernel(
    const unsigned short* __restrict__ an, const unsigned short* __restrict__ bnat,
    const float* __restrict__ bias, const int* __restrict__ assign,
    const unsigned long long* __restrict__ maskp,
    float* __restrict__ out) {
  const int t = threadIdx.x;
  const int l = t & 63;
  const int w = t >> 6;          // 0..7
  const int wm = w & 1;
  const int wn = w >> 1;         // 0..3
  const int lr = l & 15;
  const int hi4 = l >> 4;

  const int bid = blockIdx.x;
  const int swz = (bid & 7) * (gridDim.x >> 3) + (bid >> 3);   // 512 % 8 == 0
  const int bm = swz >> 4, bn = swz & 15;
  const int m0 = bm * 256, n0 = bn * 256;

  const unsigned short* pA = an   + ((size_t)bm * 32768 + wm * 64 + l) * 8;
  const unsigned short* pB = bnat + ((size_t)bn * 32768 + wn * 64 + l) * 8;

  f32x4 acc[8][4];
  #pragma unroll
  for (int i = 0; i < 8; ++i)
    #pragma unroll
    for (int j = 0; j < 4; ++j) acc[i][j] = {0.f, 0.f, 0.f, 0.f};

  struct Frags { bf16x8 a[2][4]; bf16x8 b[2][2]; };
  Frags P0, P1;

#define LOADP(P, S) do {                                                       \
    _Pragma("unroll")                                                          \
    for (int _Ha = 0; _Ha < 2; ++_Ha)                                          \
      _Pragma("unroll")                                                        \
      for (int _mi = 0; _mi < 4; ++_mi)                                        \
        P.a[_Ha][_mi] = *(const bf16x8*)(pA + ((S) * 1024 + _Ha * 512 + _mi * 128) * 8); \
    _Pragma("unroll")                                                          \
    for (int _Hb = 0; _Hb < 2; ++_Hb)                                          \
      _Pragma("unroll")                                                        \
      for (int _ni = 0; _ni < 2; ++_ni)                                        \
        P.b[_Hb][_ni] = *(const bf16x8*)(pB + ((S) * 1024 + _Hb * 512 + _ni * 256) * 8); \
  } while (0)

#define MFMAP(P) do {                                                          \
    __builtin_amdgcn_s_setprio(1);                                             \
    _Pragma("unroll")                                                          \
    for (int _Ha = 0; _Ha < 2; ++_Ha)                                          \
      _Pragma("unroll")                                                        \
      for (int _mi = 0; _mi < 4; ++_mi)                                        \
        _Pragma("unroll")                                                      \
        for (int _Hb = 0; _Hb < 2; ++_Hb)                                      \
          _Pragma("unroll")                                                    \
          for (int _ni = 0; _ni < 2; ++_ni)                                    \
            acc[_Ha * 4 + _mi][_Hb * 2 + _ni] =                                \
                __builtin_amdgcn_mfma_f32_16x16x32_bf16(                       \
                    P.a[_Ha][_mi], P.b[_Hb][_ni],                              \
                    acc[_Ha * 4 + _mi][_Hb * 2 + _ni], 0, 0, 0);               \
    __builtin_amdgcn_s_setprio(0);                                             \
  } while (0)

  LOADP(P0, 0);
  for (int s = 0; s < 30; s += 2) {
    LOADP(P1, s + 1);
    MFMAP(P0);
    LOADP(P0, s + 2);
    MFMAP(P1);
  }
  LOADP(P1, 31);
  MFMAP(P0);
  MFMAP(P1);

  // ---- epilogue: fused mask + bias ----
  const unsigned long long mask = *maskp;
  #pragma unroll
  for (int Hb = 0; Hb < 2; ++Hb) {
    #pragma unroll
    for (int ni = 0; ni < 2; ++ni) {
      const int col = n0 + Hb * 128 + ni * 64 + wn * 16 + lr;
      const int a = assign[col];
      const bool act = (mask >> a) & 1ull;
      const float bv = bias[col];
      #pragma unroll
      for (int Ha = 0; Ha < 2; ++Ha) {
        #pragma unroll
        for (int mi = 0; mi < 4; ++mi) {
          const int rowb = m0 + Ha * 128 + mi * 32 + wm * 16 + hi4 * 4;
          #pragma unroll
          for (int j = 0; j < 4; ++j) {
            out[(size_t)(rowb + j) * N_COLS + col] =
                act ? (acc[Ha * 4 + mi][Hb * 2 + ni][j] + bv) : 0.0f;
          }
        }
      }
    }
  }
#undef LOADP
#undef MFMAP
}

extern "C" void kernel_launch(void* const* d_in, const int* in_sizes, int n_in,
                              void* d_out, int out_size, void* d_ws, size_t ws_size,
                              hipStream_t stream) {
  const float* x    = (const float*)d_in[0];
  const float* wgt  = (const float*)d_in[1];
  const float* bias = (const float*)d_in[2];
  const float* cent = (const float*)d_in[3];
  const int* assign = (const int*)d_in[4];
  float* out = (float*)d_out;

  unsigned long long* mask = (unsigned long long*)d_ws;
  unsigned short* an   = (unsigned short*)((char*)d_ws + 256);
  unsigned short* bnat = an + (size_t)A_GROUPS * 8;    // +16 MB
  unsigned short* cb   = bnat + (size_t)B_GROUPS * 8;  // +8 MB (cb: 128 KB)

  const unsigned total_groups = A_GROUPS + B_GROUPS + C_GROUPS;
  hipLaunchKernelGGL(convert_kernel, dim3(total_groups / 256), dim3(256), 0, stream,
                     x, wgt, cent, an, bnat, cb, mask);
  hipLaunchKernelGGL(routing_mfma_kernel, dim3(256), dim3(64), 0, stream,
                     an, cb, mask);
  hipLaunchKernelGGL(gemm_kernel, dim3((M_ROWS / 256) * (N_COLS / 256)), dim3(512), 0, stream,
                     an, bnat, bias, assign, mask, out);
}